// Round 1
// baseline (615.026 us; speedup 1.0000x reference)
//
#include <hip/hip_runtime.h>
#include <hip/hip_bf16.h>
#include <cstddef>

// ---------------------------------------------------------------------------
// SAGEBlock: 3-layer GraphSAGE (mean aggr) on N=50000 nodes, E=800000 edges.
//   h1 = relu(agg(x)@Wl1 + x@Wr1 + b1)        F: 128 -> 256
//   h2 = relu(agg(h1)@Wl2 + h1@Wr2 + b2)      F: 256 -> 128
//   out= sigmoid(agg(h2)@Wl3 + h2@Wr3 + b3)   F: 128 -> 64
// Key trick: agg is linear => agg(h)@Wl == agg(h@Wl); aggregate at the
// narrower width (128/128/64) to cut gather traffic.
// ---------------------------------------------------------------------------

// ---------------- CSR build ----------------

__global__ void k_degree(const int* __restrict__ dst, int* __restrict__ deg, int E) {
    int e = blockIdx.x * blockDim.x + threadIdx.x;
    if (e < E) atomicAdd(&deg[dst[e]], 1);
}

// per-block exclusive scan (1024 elems/block), writes block totals
__global__ void k_scan1(const int* __restrict__ deg, int* __restrict__ excl,
                        int* __restrict__ bsum, int n) {
    __shared__ int sh[1024];
    int t = threadIdx.x;
    int i = blockIdx.x * 1024 + t;
    int v = (i < n) ? deg[i] : 0;
    sh[t] = v;
    __syncthreads();
    for (int off = 1; off < 1024; off <<= 1) {
        int add = (t >= off) ? sh[t - off] : 0;
        __syncthreads();
        sh[t] += add;
        __syncthreads();
    }
    if (i < n) excl[i] = sh[t] - v;
    if (t == 1023) bsum[blockIdx.x] = sh[t];
}

__global__ void k_scan2(int* __restrict__ bsum, int nb) {
    if (blockIdx.x == 0 && threadIdx.x == 0) {
        int run = 0;
        for (int b = 0; b < nb; ++b) { int v = bsum[b]; bsum[b] = run; run += v; }
    }
}

__global__ void k_scan3(int* __restrict__ row_start, const int* __restrict__ bsum, int n) {
    int i = blockIdx.x * blockDim.x + threadIdx.x;
    if (i < n) row_start[i] += bsum[i >> 10];
}

__global__ void k_fill(const int* __restrict__ src, const int* __restrict__ dst,
                       const int* __restrict__ row_start, int* __restrict__ fill,
                       int* __restrict__ csr_src, int E) {
    int e = blockIdx.x * blockDim.x + threadIdx.x;
    if (e < E) {
        int d = dst[e];
        int p = row_start[d] + atomicAdd(&fill[d], 1);
        csr_src[p] = src[e];
    }
}

// ---------------- mean aggregation (gather over CSR) ----------------

template <int F>
__global__ void agg_k(const float* __restrict__ in, const int* __restrict__ csr_src,
                      const int* __restrict__ row_start, const int* __restrict__ deg,
                      float* __restrict__ out) {
    int node = blockIdx.x;
    int t = threadIdx.x;                 // blockDim.x == F
    int start = row_start[node];
    int d = deg[node];
    float acc = 0.f;
    for (int j = 0; j < d; ++j) {
        int s = csr_src[start + j];      // broadcast load (same addr all lanes)
        acc += in[(size_t)s * F + t];
    }
    out[(size_t)node * F + t] = acc / (float)(d > 0 ? d : 1);
}

// ---------------- fp32 tiled GEMM, fused epilogue ----------------
// C[M,N] = act( A1[M,K1]@W1[K1,N] (+ A2[M,K2]@W2[K2,N]) (+ addv[M,N]) (+ bias[N]) )
// ACT: 0 = none, 1 = relu, 2 = sigmoid

template <int ACT>
__global__ __launch_bounds__(256)
void gemm_k(const float* __restrict__ A1, const float* __restrict__ W1, int K1,
            const float* __restrict__ A2, const float* __restrict__ W2, int K2,
            const float* __restrict__ addv, const float* __restrict__ bias,
            float* __restrict__ C, int M, int N) {
    const int bm = blockIdx.x * 64;
    const int bn = blockIdx.y * 64;
    const int tid = threadIdx.x;
    const int tx = tid & 15;   // n
    const int ty = tid >> 4;   // m
    __shared__ float As[16][68];   // [k][m], pad keeps 16B align + no conflicts
    __shared__ float Bs[16][68];   // [k][n]
    float acc[4][4] = {};

    for (int pair = 0; pair < 2; ++pair) {
        const float* A = pair ? A2 : A1;
        const float* W = pair ? W2 : W1;
        const int K = pair ? K2 : K1;
        if (A == nullptr || K == 0) continue;
        for (int k0 = 0; k0 < K; k0 += 16) {
            {   // A tile: 64 rows x 16 k
                int kk = tid & 15;
                int m0 = tid >> 4;
                #pragma unroll
                for (int it = 0; it < 4; ++it) {
                    int m = m0 + it * 16;
                    int gm = bm + m;
                    As[kk][m] = (gm < M) ? A[(size_t)gm * K + k0 + kk] : 0.f;
                }
            }
            {   // B tile: 16 k x 64 n
                int nn = tid & 63;
                int kk0 = tid >> 6;
                #pragma unroll
                for (int it = 0; it < 4; ++it) {
                    int kk = kk0 + it * 4;
                    Bs[kk][nn] = W[(size_t)(k0 + kk) * N + bn + nn];
                }
            }
            __syncthreads();
            #pragma unroll
            for (int kk = 0; kk < 16; ++kk) {
                float a[4], b[4];
                #pragma unroll
                for (int i = 0; i < 4; ++i) a[i] = As[kk][ty * 4 + i];
                #pragma unroll
                for (int j = 0; j < 4; ++j) b[j] = Bs[kk][tx * 4 + j];
                #pragma unroll
                for (int i = 0; i < 4; ++i)
                    #pragma unroll
                    for (int j = 0; j < 4; ++j)
                        acc[i][j] += a[i] * b[j];
            }
            __syncthreads();
        }
    }

    #pragma unroll
    for (int i = 0; i < 4; ++i) {
        int gm = bm + ty * 4 + i;
        if (gm >= M) continue;
        #pragma unroll
        for (int j = 0; j < 4; ++j) {
            int gn = bn + tx * 4 + j;
            float v = acc[i][j];
            if (addv) v += addv[(size_t)gm * N + gn];
            if (bias) v += bias[gn];
            if (ACT == 1) v = fmaxf(v, 0.f);
            else if (ACT == 2) v = 1.f / (1.f + expf(-v));
            C[(size_t)gm * N + gn] = v;
        }
    }
}

// ---------------------------------------------------------------------------

extern "C" void kernel_launch(void* const* d_in, const int* in_sizes, int n_in,
                              void* d_out, int out_size, void* d_ws, size_t ws_size,
                              hipStream_t stream) {
    const float* x   = (const float*)d_in[0];
    const int*   ei  = (const int*)d_in[1];
    const float* Wl1 = (const float*)d_in[2];
    const float* Wr1 = (const float*)d_in[3];
    const float* b1  = (const float*)d_in[4];
    const float* Wl2 = (const float*)d_in[5];
    const float* Wr2 = (const float*)d_in[6];
    const float* b2  = (const float*)d_in[7];
    const float* Wl3 = (const float*)d_in[8];
    const float* Wr3 = (const float*)d_in[9];
    const float* b3  = (const float*)d_in[10];

    const int M = in_sizes[0] / 128;   // 50000
    const int E = in_sizes[1] / 2;     // 800000
    const int* src = ei;
    const int* dst = ei + E;

    // workspace bump allocator (256B aligned)
    char* w = (char*)d_ws;
    auto alloc = [&](size_t bytes) -> void* {
        void* p = (void*)w;
        w += (bytes + 255) & ~(size_t)255;
        return p;
    };
    int* deg       = (int*)alloc((size_t)M * 4);
    int* row_start = (int*)alloc((size_t)M * 4);
    int* fill      = (int*)alloc((size_t)M * 4);
    int* bsum      = (int*)alloc(256 * 4);
    int* csr_src   = (int*)alloc((size_t)E * 4);
    float* A  = (float*)alloc((size_t)M * 128 * 4);  // aggx / t2 / h2
    float* H  = (float*)alloc((size_t)M * 256 * 4);  // h1
    float* Cb = (float*)alloc((size_t)M * 128 * 4);  // agg2 / t3
    float* D  = (float*)alloc((size_t)M * 64 * 4);   // agg3
    (void)ws_size; (void)n_in; (void)out_size;

    hipMemsetAsync(deg, 0, (size_t)M * 4, stream);
    hipMemsetAsync(fill, 0, (size_t)M * 4, stream);

    // CSR build
    k_degree<<<(E + 255) / 256, 256, 0, stream>>>(dst, deg, E);
    const int nb = (M + 1023) / 1024;
    k_scan1<<<nb, 1024, 0, stream>>>(deg, row_start, bsum, M);
    k_scan2<<<1, 64, 0, stream>>>(bsum, nb);
    k_scan3<<<(M + 255) / 256, 256, 0, stream>>>(row_start, bsum, M);
    k_fill<<<(E + 255) / 256, 256, 0, stream>>>(src, dst, row_start, fill, csr_src, E);

    // ---- layer 1: aggregate x (width 128), then fused dual GEMM
    agg_k<128><<<M, 128, 0, stream>>>(x, csr_src, row_start, deg, A);
    dim3 g1((M + 63) / 64, 256 / 64);
    gemm_k<1><<<g1, 256, 0, stream>>>(A, Wl1, 128, x, Wr1, 128,
                                      nullptr, b1, H, M, 256);

    // ---- layer 2: t2 = h1@Wl2 (width 128), aggregate, then h2
    dim3 g2((M + 63) / 64, 128 / 64);
    gemm_k<0><<<g2, 256, 0, stream>>>(H, Wl2, 256, nullptr, nullptr, 0,
                                      nullptr, nullptr, A, M, 128);      // t2 -> A
    agg_k<128><<<M, 128, 0, stream>>>(A, csr_src, row_start, deg, Cb);   // agg2 -> Cb
    gemm_k<1><<<g2, 256, 0, stream>>>(H, Wr2, 256, nullptr, nullptr, 0,
                                      Cb, b2, A, M, 128);                // h2 -> A

    // ---- layer 3: t3 = h2@Wl3 (width 64), aggregate, then out
    dim3 g3((M + 63) / 64, 64 / 64);
    gemm_k<0><<<g3, 256, 0, stream>>>(A, Wl3, 128, nullptr, nullptr, 0,
                                      nullptr, nullptr, Cb, M, 64);      // t3 -> Cb
    agg_k<64><<<M, 64, 0, stream>>>(Cb, csr_src, row_start, deg, D);     // agg3 -> D
    gemm_k<2><<<g3, 256, 0, stream>>>(A, Wr3, 128, nullptr, nullptr, 0,
                                      D, b3, (float*)d_out, M, 64);      // out
}

// Round 2
// 346.593 us; speedup vs baseline: 1.7745x; 1.7745x over previous
//
#include <hip/hip_runtime.h>
#include <cstddef>

// ---------------------------------------------------------------------------
// SAGEBlock: 3-layer GraphSAGE (mean aggr), N=50000, E=800000.
//   h1 = relu(agg(x)@Wl1 + x@Wr1 + b1)        128 -> 256
//   h2 = relu(agg(h1@Wl2) + h1@Wr2 + b2)      256 -> 128  (agg/@ commute)
//   out= sigmoid(agg(h2@Wl3) + h2@Wr3 + b3)   128 -> 64
// R2: bf16 MFMA GEMMs (16x16x32, fp32 accum), XOR-swizzled LDS tiles,
//     bf16 intermediates to halve gather traffic.
// ---------------------------------------------------------------------------

using frag  = __attribute__((ext_vector_type(8))) short;   // 8 bf16 = 4 VGPR
using f32x4 = __attribute__((ext_vector_type(4))) float;

__device__ __forceinline__ ushort f2bf(float f) {
    union { float f; unsigned u; } v; v.f = f;
    unsigned r = v.u + 0x7FFF + ((v.u >> 16) & 1);   // RNE
    return (ushort)(r >> 16);
}
__device__ __forceinline__ float bf2f(ushort u) {
    union { unsigned u; float f; } v; v.u = ((unsigned)u) << 16;
    return v.f;
}

// ---------------- CSR build ----------------

__global__ void k_degree(const int* __restrict__ dst, int* __restrict__ deg, int E) {
    int e = blockIdx.x * blockDim.x + threadIdx.x;
    if (e < E) atomicAdd(&deg[dst[e]], 1);
}

__global__ void k_scan1(const int* __restrict__ deg, int* __restrict__ excl,
                        int* __restrict__ bsum, int n) {
    __shared__ int sh[1024];
    int t = threadIdx.x;
    int i = blockIdx.x * 1024 + t;
    int v = (i < n) ? deg[i] : 0;
    sh[t] = v;
    __syncthreads();
    for (int off = 1; off < 1024; off <<= 1) {
        int add = (t >= off) ? sh[t - off] : 0;
        __syncthreads();
        sh[t] += add;
        __syncthreads();
    }
    if (i < n) excl[i] = sh[t] - v;
    if (t == 1023) bsum[blockIdx.x] = sh[t];
}

__global__ void k_scan2(int* __restrict__ bsum, int nb) {
    if (blockIdx.x == 0 && threadIdx.x == 0) {
        int run = 0;
        for (int b = 0; b < nb; ++b) { int v = bsum[b]; bsum[b] = run; run += v; }
    }
}

__global__ void k_scan3(int* __restrict__ row_start, const int* __restrict__ bsum, int n) {
    int i = blockIdx.x * blockDim.x + threadIdx.x;
    if (i < n) row_start[i] += bsum[i >> 10];
}

__global__ void k_fill(const int* __restrict__ src, const int* __restrict__ dst,
                       const int* __restrict__ row_start, int* __restrict__ fill,
                       int* __restrict__ csr_src, int E) {
    int e = blockIdx.x * blockDim.x + threadIdx.x;
    if (e < E) {
        int d = dst[e];
        int p = row_start[d] + atomicAdd(&fill[d], 1);
        csr_src[p] = src[e];
    }
}

// ---------------- dtype converts ----------------

__global__ void k_cvt_x(const float* __restrict__ in, ushort* __restrict__ out, int n4) {
    int i = blockIdx.x * blockDim.x + threadIdx.x;
    if (i < n4) {
        float4 v = ((const float4*)in)[i];
        ushort4 o; o.x = f2bf(v.x); o.y = f2bf(v.y); o.z = f2bf(v.z); o.w = f2bf(v.w);
        ((ushort4*)out)[i] = o;
    }
}

// W[K][N] f32 -> WT[N][K] bf16
__global__ void k_cvt_w(const float* __restrict__ W, ushort* __restrict__ WT,
                        int K, int N) {
    int t = blockIdx.x * blockDim.x + threadIdx.x;
    if (t < K * N) {
        int k = t / N, n = t % N;
        WT[(size_t)n * K + k] = f2bf(W[t]);
    }
}

// ---------------- mean aggregation (CSR gather, bf16 in) ----------------
// 4 waves/block, one node per wave. F/64 elems per lane.

template <int F, int OUTF32>
__global__ __launch_bounds__(256)
void agg_bf(const ushort* __restrict__ in, const int* __restrict__ csr_src,
            const int* __restrict__ row_start, const int* __restrict__ deg,
            void* __restrict__ out, int nN) {
    int node = blockIdx.x * 4 + (threadIdx.x >> 6);
    if (node >= nN) return;
    int lane = threadIdx.x & 63;
    constexpr int EPL = F / 64;               // 1 or 2
    int start = row_start[node];
    int d = deg[node];
    float acc0 = 0.f, acc1 = 0.f;
    int j = 0;
    for (; j + 4 <= d; j += 4) {
        int s0 = csr_src[start + j + 0];
        int s1 = csr_src[start + j + 1];
        int s2 = csr_src[start + j + 2];
        int s3 = csr_src[start + j + 3];
        if (EPL == 2) {
            ushort2 u0 = *(const ushort2*)(in + (size_t)s0 * F + lane * 2);
            ushort2 u1 = *(const ushort2*)(in + (size_t)s1 * F + lane * 2);
            ushort2 u2 = *(const ushort2*)(in + (size_t)s2 * F + lane * 2);
            ushort2 u3 = *(const ushort2*)(in + (size_t)s3 * F + lane * 2);
            acc0 += bf2f(u0.x) + bf2f(u1.x) + bf2f(u2.x) + bf2f(u3.x);
            acc1 += bf2f(u0.y) + bf2f(u1.y) + bf2f(u2.y) + bf2f(u3.y);
        } else {
            acc0 += bf2f(in[(size_t)s0 * F + lane]) + bf2f(in[(size_t)s1 * F + lane])
                  + bf2f(in[(size_t)s2 * F + lane]) + bf2f(in[(size_t)s3 * F + lane]);
        }
    }
    for (; j < d; ++j) {
        int s = csr_src[start + j];
        if (EPL == 2) {
            ushort2 u = *(const ushort2*)(in + (size_t)s * F + lane * 2);
            acc0 += bf2f(u.x); acc1 += bf2f(u.y);
        } else {
            acc0 += bf2f(in[(size_t)s * F + lane]);
        }
    }
    float inv = 1.f / (float)(d > 0 ? d : 1);
    acc0 *= inv; acc1 *= inv;
    if (OUTF32) {
        float* o = (float*)out + (size_t)node * F + lane * EPL;
        o[0] = acc0; if (EPL == 2) o[1] = acc1;
    } else {
        ushort* o = (ushort*)out + (size_t)node * F + lane * EPL;
        o[0] = f2bf(acc0); if (EPL == 2) o[1] = f2bf(acc1);
    }
}

// ---------------- bf16 MFMA GEMM, fused epilogue ----------------
// C[M,N] = act( A1@B1^T (+ A2@B2^T) (+ addv) (+ bias) )
// A: [M][K] bf16 row-major.  B (weights): [N][K] bf16 (pre-transposed).
// BK=64. LDS tiles XOR-swizzled: byte ^= (row&7)<<4 within each 128B row.

template <int BM, int BN, int WM, int WN, int ACT, int OUTBF>
__global__ __launch_bounds__(WM * WN * 64)
void mgemm(const ushort* __restrict__ A1, const ushort* __restrict__ B1, int K1,
           const ushort* __restrict__ A2, const ushort* __restrict__ B2, int K2,
           const float* __restrict__ addv, const float* __restrict__ bias,
           void* __restrict__ Cout, int M, int N) {
    constexpr int NT = WM * WN * 64;
    constexpr int MF = BM / (WM * 16);
    constexpr int NF = BN / (WN * 16);
    __shared__ char lds[(BM + BN) * 128];     // (BM+BN) rows x 64 bf16
    char* As = lds;
    char* Bs = lds + BM * 128;

    const int tid  = threadIdx.x;
    const int lane = tid & 63;
    const int wid  = tid >> 6;
    const int wm   = wid % WM, wn = wid / WM;
    const int bm   = blockIdx.x * BM;
    const int bn   = blockIdx.y * BN;
    const int l15  = lane & 15;
    const int lhi  = lane >> 4;

    f32x4 acc[MF][NF] = {};

    for (int pass = 0; pass < 2; ++pass) {
        const ushort* A = pass ? A2 : A1;
        const ushort* B = pass ? B2 : B1;
        const int K = pass ? K2 : K1;
        if (A == nullptr) continue;
        for (int k0 = 0; k0 < K; k0 += 64) {
            #pragma unroll
            for (int it = 0; it < BM * 8 / NT; ++it) {       // stage A
                int flat = it * NT + tid;
                int row = flat >> 3;
                int cb = (flat & 7) * 16;
                frag v = {};
                int gr = bm + row;
                if (gr < M) v = *(const frag*)(A + (size_t)gr * K + k0 + (flat & 7) * 8);
                *(frag*)(As + row * 128 + (cb ^ ((row & 7) << 4))) = v;
            }
            #pragma unroll
            for (int it = 0; it < BN * 8 / NT; ++it) {       // stage B
                int flat = it * NT + tid;
                int row = flat >> 3;
                int cb = (flat & 7) * 16;
                frag v = *(const frag*)(B + (size_t)(bn + row) * K + k0 + (flat & 7) * 8);
                *(frag*)(Bs + row * 128 + (cb ^ ((row & 7) << 4))) = v;
            }
            __syncthreads();
            #pragma unroll
            for (int ks = 0; ks < 2; ++ks) {
                const int kb = ks * 64 + lhi * 16;
                frag a[MF], b[NF];
                #pragma unroll
                for (int mf = 0; mf < MF; ++mf) {
                    int row = wm * MF * 16 + mf * 16 + l15;
                    a[mf] = *(const frag*)(As + row * 128 + (kb ^ ((row & 7) << 4)));
                }
                #pragma unroll
                for (int nf = 0; nf < NF; ++nf) {
                    int row = wn * NF * 16 + nf * 16 + l15;
                    b[nf] = *(const frag*)(Bs + row * 128 + (kb ^ ((row & 7) << 4)));
                }
                #pragma unroll
                for (int mf = 0; mf < MF; ++mf)
                    #pragma unroll
                    for (int nf = 0; nf < NF; ++nf)
                        acc[mf][nf] = __builtin_amdgcn_mfma_f32_16x16x32_bf16(
                            a[mf], b[nf], acc[mf][nf], 0, 0, 0);
            }
            __syncthreads();
        }
    }

    #pragma unroll
    for (int mf = 0; mf < MF; ++mf) {
        #pragma unroll
        for (int r = 0; r < 4; ++r) {
            int gm = bm + wm * MF * 16 + mf * 16 + lhi * 4 + r;
            if (gm >= M) continue;
            #pragma unroll
            for (int nf = 0; nf < NF; ++nf) {
                int gn = bn + wn * NF * 16 + nf * 16 + l15;
                float v = acc[mf][nf][r];
                if (addv) v += addv[(size_t)gm * N + gn];
                if (bias) v += bias[gn];
                if (ACT == 1) v = fmaxf(v, 0.f);
                else if (ACT == 2) v = 1.f / (1.f + __expf(-v));
                if (OUTBF) ((ushort*)Cout)[(size_t)gm * N + gn] = f2bf(v);
                else       ((float*)Cout)[(size_t)gm * N + gn] = v;
            }
        }
    }
}

// ---------------------------------------------------------------------------

extern "C" void kernel_launch(void* const* d_in, const int* in_sizes, int n_in,
                              void* d_out, int out_size, void* d_ws, size_t ws_size,
                              hipStream_t stream) {
    const float* x   = (const float*)d_in[0];
    const int*   ei  = (const int*)d_in[1];
    const float* Wl1 = (const float*)d_in[2];
    const float* Wr1 = (const float*)d_in[3];
    const float* b1  = (const float*)d_in[4];
    const float* Wl2 = (const float*)d_in[5];
    const float* Wr2 = (const float*)d_in[6];
    const float* b2  = (const float*)d_in[7];
    const float* Wl3 = (const float*)d_in[8];
    const float* Wr3 = (const float*)d_in[9];
    const float* b3  = (const float*)d_in[10];

    const int M = in_sizes[0] / 128;   // 50000
    const int E = in_sizes[1] / 2;     // 800000
    const int* src = ei;
    const int* dst = ei + E;

    char* w = (char*)d_ws;
    auto alloc = [&](size_t bytes) -> void* {
        void* p = (void*)w;
        w += (bytes + 255) & ~(size_t)255;
        return p;
    };
    int* deg       = (int*)alloc((size_t)M * 4);
    int* row_start = (int*)alloc((size_t)M * 4);
    int* fill      = (int*)alloc((size_t)M * 4);
    int* bsum      = (int*)alloc(256 * 4);
    int* csr_src   = (int*)alloc((size_t)E * 4);
    ushort* Wl1t = (ushort*)alloc(128 * 256 * 2);
    ushort* Wr1t = (ushort*)alloc(128 * 256 * 2);
    ushort* Wl2t = (ushort*)alloc(256 * 128 * 2);
    ushort* Wr2t = (ushort*)alloc(256 * 128 * 2);
    ushort* Wl3t = (ushort*)alloc(128 * 64 * 2);
    ushort* Wr3t = (ushort*)alloc(128 * 64 * 2);
    ushort* x_bf = (ushort*)alloc((size_t)M * 128 * 2);   // P0: x_bf -> t2
    ushort* aggx = (ushort*)alloc((size_t)M * 128 * 2);   // P1: aggx -> t3
    ushort* h1   = (ushort*)alloc((size_t)M * 256 * 2);   // P2
    ushort* h2   = (ushort*)alloc((size_t)M * 128 * 2);   // P3
    float*  agg2 = (float*)alloc((size_t)M * 128 * 4);    // P4: agg2 -> agg3
    ushort* t2 = x_bf;
    ushort* t3 = aggx;
    float*  agg3 = agg2;
    (void)ws_size; (void)n_in; (void)out_size;

    hipMemsetAsync(deg, 0, (size_t)M * 4, stream);
    hipMemsetAsync(fill, 0, (size_t)M * 4, stream);

    // CSR build
    k_degree<<<(E + 255) / 256, 256, 0, stream>>>(dst, deg, E);
    const int nb = (M + 1023) / 1024;
    k_scan1<<<nb, 1024, 0, stream>>>(deg, row_start, bsum, M);
    k_scan2<<<1, 64, 0, stream>>>(bsum, nb);
    k_scan3<<<(M + 255) / 256, 256, 0, stream>>>(row_start, bsum, M);
    k_fill<<<(E + 255) / 256, 256, 0, stream>>>(src, dst, row_start, fill, csr_src, E);

    // converts
    k_cvt_x<<<(M * 128 / 4 + 255) / 256, 256, 0, stream>>>(x, x_bf, M * 128 / 4);
    k_cvt_w<<<(128 * 256 + 255) / 256, 256, 0, stream>>>(Wl1, Wl1t, 128, 256);
    k_cvt_w<<<(128 * 256 + 255) / 256, 256, 0, stream>>>(Wr1, Wr1t, 128, 256);
    k_cvt_w<<<(256 * 128 + 255) / 256, 256, 0, stream>>>(Wl2, Wl2t, 256, 128);
    k_cvt_w<<<(256 * 128 + 255) / 256, 256, 0, stream>>>(Wr2, Wr2t, 256, 128);
    k_cvt_w<<<(128 * 64 + 255) / 256, 256, 0, stream>>>(Wl3, Wl3t, 128, 64);
    k_cvt_w<<<(128 * 64 + 255) / 256, 256, 0, stream>>>(Wr3, Wr3t, 128, 64);

    const int gx = (M + 127) / 128;           // 391
    const int gagg = (M + 3) / 4;             // 12500

    // ---- layer 1
    agg_bf<128, 0><<<gagg, 256, 0, stream>>>(x_bf, csr_src, row_start, deg, aggx, M);
    mgemm<128, 128, 2, 2, 1, 1><<<dim3(gx, 2), 256, 0, stream>>>(
        aggx, Wl1t, 128, x_bf, Wr1t, 128, nullptr, b1, h1, M, 256);

    // ---- layer 2
    mgemm<128, 128, 2, 2, 0, 1><<<dim3(gx, 1), 256, 0, stream>>>(
        h1, Wl2t, 256, nullptr, nullptr, 0, nullptr, nullptr, t2, M, 128);
    agg_bf<128, 1><<<gagg, 256, 0, stream>>>(t2, csr_src, row_start, deg, agg2, M);
    mgemm<128, 128, 2, 2, 1, 1><<<dim3(gx, 1), 256, 0, stream>>>(
        h1, Wr2t, 256, nullptr, nullptr, 0, agg2, b2, h2, M, 128);

    // ---- layer 3
    mgemm<128, 64, 2, 2, 0, 1><<<dim3(gx, 1), 256, 0, stream>>>(
        h2, Wl3t, 128, nullptr, nullptr, 0, nullptr, nullptr, t3, M, 64);
    agg_bf<64, 1><<<gagg, 256, 0, stream>>>(t3, csr_src, row_start, deg, agg3, M);
    mgemm<128, 64, 2, 2, 2, 0><<<dim3(gx, 1), 256, 0, stream>>>(
        h2, Wr3t, 128, nullptr, nullptr, 0, agg3, b3, (float*)d_out, M, 64);
}

// Round 3
// 286.893 us; speedup vs baseline: 2.1438x; 1.2081x over previous
//
#include <hip/hip_runtime.h>
#include <cstddef>

// ---------------------------------------------------------------------------
// SAGEBlock: 3-layer GraphSAGE (mean aggr), N=50000, E=800000.
//   h1 = relu(agg(x)@Wl1 + x@Wr1 + b1)              128 -> 256
//   h2 = relu(agg(h1@Wl2) + h1@Wr2 + b2)            256 -> 128
//   out= sigmoid(agg(h2@Wl3) + h2@Wr3 + b3)         128 -> 64
// R3: 64x64 GEMM tiles (grid 3128 blocks -> occupancy), weight-concat so each
//     layer is ONE GEMM ([t|u] = h@[Wl|Wr]) + agg + elementwise finish.
// ---------------------------------------------------------------------------

using frag  = __attribute__((ext_vector_type(8))) short;   // 8 bf16
using f32x4 = __attribute__((ext_vector_type(4))) float;
using u16x8 = __attribute__((ext_vector_type(8))) unsigned short;

__device__ __forceinline__ ushort f2bf(float f) {
    union { float f; unsigned u; } v; v.f = f;
    unsigned r = v.u + 0x7FFF + ((v.u >> 16) & 1);   // RNE
    return (ushort)(r >> 16);
}
__device__ __forceinline__ float bf2f(ushort u) {
    union { unsigned u; float f; } v; v.u = ((unsigned)u) << 16;
    return v.f;
}

// ---------------- CSR build ----------------

__global__ void k_degree(const int* __restrict__ dst, int* __restrict__ deg, int E) {
    int e = blockIdx.x * blockDim.x + threadIdx.x;
    if (e < E) atomicAdd(&deg[dst[e]], 1);
}

__global__ void k_scan1(const int* __restrict__ deg, int* __restrict__ excl,
                        int* __restrict__ bsum, int n) {
    __shared__ int sh[1024];
    int t = threadIdx.x;
    int i = blockIdx.x * 1024 + t;
    int v = (i < n) ? deg[i] : 0;
    sh[t] = v;
    __syncthreads();
    for (int off = 1; off < 1024; off <<= 1) {
        int add = (t >= off) ? sh[t - off] : 0;
        __syncthreads();
        sh[t] += add;
        __syncthreads();
    }
    if (i < n) excl[i] = sh[t] - v;
    if (t == 1023) bsum[blockIdx.x] = sh[t];
}

__global__ void k_scan2(int* __restrict__ bsum, int nb) {
    if (blockIdx.x == 0 && threadIdx.x == 0) {
        int run = 0;
        for (int b = 0; b < nb; ++b) { int v = bsum[b]; bsum[b] = run; run += v; }
    }
}

__global__ void k_scan3(int* __restrict__ row_start, const int* __restrict__ bsum, int n) {
    int i = blockIdx.x * blockDim.x + threadIdx.x;
    if (i < n) row_start[i] += bsum[i >> 10];
}

__global__ void k_fill(const int* __restrict__ src, const int* __restrict__ dst,
                       const int* __restrict__ row_start, int* __restrict__ fill,
                       int* __restrict__ csr_src, int E) {
    int e = blockIdx.x * blockDim.x + threadIdx.x;
    if (e < E) {
        int d = dst[e];
        int p = row_start[d] + atomicAdd(&fill[d], 1);
        csr_src[p] = src[e];
    }
}

// ---------------- dtype converts ----------------

__global__ void k_cvt_x(const float* __restrict__ in, ushort* __restrict__ out, int n4) {
    int i = blockIdx.x * blockDim.x + threadIdx.x;
    if (i < n4) {
        float4 v = ((const float4*)in)[i];
        ushort4 o; o.x = f2bf(v.x); o.y = f2bf(v.y); o.z = f2bf(v.z); o.w = f2bf(v.w);
        ((ushort4*)out)[i] = o;
    }
}

// all 6 weight transposes in one dispatch: W[K][N] f32 -> WT[N][K] bf16
struct CvtDesc {
    const float* s[6];
    ushort*      d[6];
    int K[6];
    int N[6];
};

__global__ void k_cvt_w6(CvtDesc c) {
    int wi = blockIdx.y;
    int t = blockIdx.x * blockDim.x + threadIdx.x;
    int K = c.K[wi], N = c.N[wi];
    if (t < K * N) {
        int k = t / N, n = t % N;
        c.d[wi][(size_t)n * K + k] = f2bf(c.s[wi][t]);
    }
}

// ---------------- mean aggregation (CSR gather, bf16 in/out) ----------------
// 4 waves/block, one node per wave.

template <int F>
__global__ __launch_bounds__(256)
void agg_bf(const ushort* __restrict__ in, const int* __restrict__ csr_src,
            const int* __restrict__ row_start, const int* __restrict__ deg,
            ushort* __restrict__ out, int nN) {
    int node = blockIdx.x * 4 + (threadIdx.x >> 6);
    if (node >= nN) return;
    int lane = threadIdx.x & 63;
    constexpr int EPL = F / 64;               // 1 or 2
    int start = row_start[node];
    int d = deg[node];
    float acc0 = 0.f, acc1 = 0.f;
    int j = 0;
    for (; j + 4 <= d; j += 4) {
        int s0 = csr_src[start + j + 0];
        int s1 = csr_src[start + j + 1];
        int s2 = csr_src[start + j + 2];
        int s3 = csr_src[start + j + 3];
        if (EPL == 2) {
            ushort2 u0 = *(const ushort2*)(in + (size_t)s0 * F + lane * 2);
            ushort2 u1 = *(const ushort2*)(in + (size_t)s1 * F + lane * 2);
            ushort2 u2 = *(const ushort2*)(in + (size_t)s2 * F + lane * 2);
            ushort2 u3 = *(const ushort2*)(in + (size_t)s3 * F + lane * 2);
            acc0 += bf2f(u0.x) + bf2f(u1.x) + bf2f(u2.x) + bf2f(u3.x);
            acc1 += bf2f(u0.y) + bf2f(u1.y) + bf2f(u2.y) + bf2f(u3.y);
        } else {
            acc0 += bf2f(in[(size_t)s0 * F + lane]) + bf2f(in[(size_t)s1 * F + lane])
                  + bf2f(in[(size_t)s2 * F + lane]) + bf2f(in[(size_t)s3 * F + lane]);
        }
    }
    for (; j < d; ++j) {
        int s = csr_src[start + j];
        if (EPL == 2) {
            ushort2 u = *(const ushort2*)(in + (size_t)s * F + lane * 2);
            acc0 += bf2f(u.x); acc1 += bf2f(u.y);
        } else {
            acc0 += bf2f(in[(size_t)s * F + lane]);
        }
    }
    float inv = 1.f / (float)(d > 0 ? d : 1);
    acc0 *= inv; acc1 *= inv;
    ushort* o = out + (size_t)node * F + lane * EPL;
    o[0] = f2bf(acc0); if (EPL == 2) o[1] = f2bf(acc1);
}

// ---------------- bf16 MFMA GEMM, fused epilogue with column split ----------
// C[M,N] = act( A1@B1^T (+ A2@B2^T) (+ bias) ); cols < nsplit -> C1, else C2.
// A: [M][K] bf16 row-major.  B: [N][K] bf16 (pre-transposed weights).
// BK=64. LDS tiles XOR-swizzled: byte ^= (row&7)<<4.

template <int BM, int BN, int WM, int WN, int ACT>
__global__ __launch_bounds__(WM * WN * 64)
void mgemm(const ushort* __restrict__ A1, const ushort* __restrict__ B1, int K1,
           const ushort* __restrict__ A2, const ushort* __restrict__ B2, int K2,
           const float* __restrict__ bias,
           ushort* __restrict__ C1, int ld1,
           ushort* __restrict__ C2, int ld2, int nsplit,
           int M, int N) {
    constexpr int NT = WM * WN * 64;
    constexpr int MF = BM / (WM * 16);
    constexpr int NF = BN / (WN * 16);
    __shared__ char lds[(BM + BN) * 128];     // rows x 64 bf16
    char* As = lds;
    char* Bs = lds + BM * 128;

    const int tid  = threadIdx.x;
    const int lane = tid & 63;
    const int wid  = tid >> 6;
    const int wm   = wid % WM, wn = wid / WM;
    const int bm   = blockIdx.x * BM;
    const int bn   = blockIdx.y * BN;
    const int l15  = lane & 15;
    const int lhi  = lane >> 4;

    f32x4 acc[MF][NF] = {};

    for (int pass = 0; pass < 2; ++pass) {
        const ushort* A = pass ? A2 : A1;
        const ushort* B = pass ? B2 : B1;
        const int K = pass ? K2 : K1;
        if (A == nullptr) continue;
        for (int k0 = 0; k0 < K; k0 += 64) {
            #pragma unroll
            for (int it = 0; it < BM * 8 / NT; ++it) {       // stage A
                int flat = it * NT + tid;
                int row = flat >> 3;
                int cb = (flat & 7) * 16;
                frag v = {};
                int gr = bm + row;
                if (gr < M) v = *(const frag*)(A + (size_t)gr * K + k0 + (flat & 7) * 8);
                *(frag*)(As + row * 128 + (cb ^ ((row & 7) << 4))) = v;
            }
            #pragma unroll
            for (int it = 0; it < BN * 8 / NT; ++it) {       // stage B
                int flat = it * NT + tid;
                int row = flat >> 3;
                int cb = (flat & 7) * 16;
                frag v = *(const frag*)(B + (size_t)(bn + row) * K + k0 + (flat & 7) * 8);
                *(frag*)(Bs + row * 128 + (cb ^ ((row & 7) << 4))) = v;
            }
            __syncthreads();
            #pragma unroll
            for (int ks = 0; ks < 2; ++ks) {
                const int kb = ks * 64 + lhi * 16;
                frag a[MF], b[NF];
                #pragma unroll
                for (int mf = 0; mf < MF; ++mf) {
                    int row = wm * MF * 16 + mf * 16 + l15;
                    a[mf] = *(const frag*)(As + row * 128 + (kb ^ ((row & 7) << 4)));
                }
                #pragma unroll
                for (int nf = 0; nf < NF; ++nf) {
                    int row = wn * NF * 16 + nf * 16 + l15;
                    b[nf] = *(const frag*)(Bs + row * 128 + (kb ^ ((row & 7) << 4)));
                }
                #pragma unroll
                for (int mf = 0; mf < MF; ++mf)
                    #pragma unroll
                    for (int nf = 0; nf < NF; ++nf)
                        acc[mf][nf] = __builtin_amdgcn_mfma_f32_16x16x32_bf16(
                            a[mf], b[nf], acc[mf][nf], 0, 0, 0);
            }
            __syncthreads();
        }
    }

    #pragma unroll
    for (int mf = 0; mf < MF; ++mf) {
        #pragma unroll
        for (int r = 0; r < 4; ++r) {
            int gm = bm + wm * MF * 16 + mf * 16 + lhi * 4 + r;
            if (gm >= M) continue;
            #pragma unroll
            for (int nf = 0; nf < NF; ++nf) {
                int gn = bn + wn * NF * 16 + nf * 16 + l15;
                float v = acc[mf][nf][r];
                if (bias) v += bias[gn];
                if (ACT == 1) v = fmaxf(v, 0.f);
                ushort o = f2bf(v);
                if (gn < nsplit) C1[(size_t)gm * ld1 + gn] = o;
                else             C2[(size_t)gm * ld2 + (gn - nsplit)] = o;
            }
        }
    }
}

// ---------------- elementwise finish: act(agg + u + b) ----------------
// ACT 1 = relu -> bf16 out; ACT 2 = sigmoid -> f32 out. 8 elems/thread.

template <int FC, int ACT>
__global__ __launch_bounds__(256)
void ew_k(const ushort* __restrict__ agg, const ushort* __restrict__ u,
          const float* __restrict__ bias, void* __restrict__ out, int total8) {
    int i = blockIdx.x * blockDim.x + threadIdx.x;
    if (i >= total8) return;
    int col = (i * 8) & (FC - 1);
    u16x8 av = *(const u16x8*)(agg + (size_t)i * 8);
    u16x8 uv = *(const u16x8*)(u + (size_t)i * 8);
    float4 b0 = *(const float4*)(bias + col);
    float4 b1 = *(const float4*)(bias + col + 4);
    float o[8];
    #pragma unroll
    for (int j = 0; j < 8; ++j) {
        float bj = (j < 4) ? (&b0.x)[j] : (&b1.x)[j - 4];
        float v = bf2f(av[j]) + bf2f(uv[j]) + bj;
        if (ACT == 1) v = fmaxf(v, 0.f);
        else          v = 1.f / (1.f + __expf(-v));
        o[j] = v;
    }
    if (ACT == 1) {
        u16x8 w;
        #pragma unroll
        for (int j = 0; j < 8; ++j) w[j] = f2bf(o[j]);
        *(u16x8*)((ushort*)out + (size_t)i * 8) = w;
    } else {
        float4* po = (float4*)out + (size_t)i * 2;
        po[0] = make_float4(o[0], o[1], o[2], o[3]);
        po[1] = make_float4(o[4], o[5], o[6], o[7]);
    }
}

// ---------------------------------------------------------------------------

extern "C" void kernel_launch(void* const* d_in, const int* in_sizes, int n_in,
                              void* d_out, int out_size, void* d_ws, size_t ws_size,
                              hipStream_t stream) {
    const float* x   = (const float*)d_in[0];
    const int*   ei  = (const int*)d_in[1];
    const float* Wl1 = (const float*)d_in[2];
    const float* Wr1 = (const float*)d_in[3];
    const float* b1  = (const float*)d_in[4];
    const float* Wl2 = (const float*)d_in[5];
    const float* Wr2 = (const float*)d_in[6];
    const float* b2  = (const float*)d_in[7];
    const float* Wl3 = (const float*)d_in[8];
    const float* Wr3 = (const float*)d_in[9];
    const float* b3  = (const float*)d_in[10];

    const int M = in_sizes[0] / 128;   // 50000
    const int E = in_sizes[1] / 2;     // 800000
    const int* src = ei;
    const int* dst = ei + E;

    char* w = (char*)d_ws;
    auto alloc = [&](size_t bytes) -> void* {
        void* p = (void*)w;
        w += (bytes + 255) & ~(size_t)255;
        return p;
    };
    int* deg       = (int*)alloc((size_t)M * 4);
    int* row_start = (int*)alloc((size_t)M * 4);
    int* fill      = (int*)alloc((size_t)M * 4);
    int* bsum      = (int*)alloc(256 * 4);
    int* csr_src   = (int*)alloc((size_t)E * 4);
    ushort* Wl1t   = (ushort*)alloc(256 * 128 * 2);       // [256][128]
    ushort* Wr1t   = (ushort*)alloc(256 * 128 * 2);       // [256][128]
    ushort* Wcat2T = (ushort*)alloc(256 * 256 * 2);       // [256][256]: Wl2|Wr2
    ushort* Wcat3T = (ushort*)alloc(128 * 128 * 2);       // [128][128]: Wl3|Wr3
    ushort* bufA = (ushort*)alloc((size_t)M * 128 * 2);   // x_bf -> t2 -> h2
    ushort* bufB = (ushort*)alloc((size_t)M * 128 * 2);   // aggx -> u2 -> t3
    ushort* bufH = (ushort*)alloc((size_t)M * 256 * 2);   // h1 -> agg3
    ushort* bufC = (ushort*)alloc((size_t)M * 128 * 2);   // agg2 -> u3
    (void)ws_size; (void)n_in; (void)out_size;

    ushort* x_bf = bufA; ushort* t2 = bufA; ushort* h2 = bufA;
    ushort* aggx = bufB; ushort* u2 = bufB; ushort* t3 = bufB;
    ushort* h1 = bufH;   ushort* agg3 = bufH;
    ushort* agg2 = bufC; ushort* u3 = bufC + (size_t)M * 64;

    hipMemsetAsync(deg, 0, (size_t)M * 4, stream);
    hipMemsetAsync(fill, 0, (size_t)M * 4, stream);

    // CSR build
    k_degree<<<(E + 255) / 256, 256, 0, stream>>>(dst, deg, E);
    const int nb = (M + 1023) / 1024;
    k_scan1<<<nb, 1024, 0, stream>>>(deg, row_start, bsum, M);
    k_scan2<<<1, 64, 0, stream>>>(bsum, nb);
    k_scan3<<<(M + 255) / 256, 256, 0, stream>>>(row_start, bsum, M);
    k_fill<<<(E + 255) / 256, 256, 0, stream>>>(src, dst, row_start, fill, csr_src, E);

    // converts
    k_cvt_x<<<(M * 128 / 4 + 255) / 256, 256, 0, stream>>>(x, x_bf, M * 128 / 4);
    CvtDesc cd;
    cd.s[0] = Wl1; cd.d[0] = Wl1t;            cd.K[0] = 128; cd.N[0] = 256;
    cd.s[1] = Wr1; cd.d[1] = Wr1t;            cd.K[1] = 128; cd.N[1] = 256;
    cd.s[2] = Wl2; cd.d[2] = Wcat2T;          cd.K[2] = 256; cd.N[2] = 128;
    cd.s[3] = Wr2; cd.d[3] = Wcat2T + 128*256; cd.K[3] = 256; cd.N[3] = 128;
    cd.s[4] = Wl3; cd.d[4] = Wcat3T;          cd.K[4] = 128; cd.N[4] = 64;
    cd.s[5] = Wr3; cd.d[5] = Wcat3T + 64*128; cd.K[5] = 128; cd.N[5] = 64;
    k_cvt_w6<<<dim3(128, 6), 256, 0, stream>>>(cd);

    const int gm64 = (M + 63) / 64;           // 782
    const int gagg = (M + 3) / 4;             // 12500

    // ---- layer 1: h1 = relu(aggx@Wl1 + x@Wr1 + b1)
    agg_bf<128><<<gagg, 256, 0, stream>>>(x_bf, csr_src, row_start, deg, aggx, M);
    mgemm<64, 64, 2, 2, 1><<<dim3(gm64, 4), 256, 0, stream>>>(
        aggx, Wl1t, 128, x_bf, Wr1t, 128, b1,
        h1, 256, nullptr, 0, 256, M, 256);

    // ---- layer 2: [t2|u2] = h1@Wcat2, agg2 = agg(t2), h2 = relu(agg2+u2+b2)
    mgemm<64, 64, 2, 2, 0><<<dim3(gm64, 4), 256, 0, stream>>>(
        h1, Wcat2T, 256, nullptr, nullptr, 0, nullptr,
        t2, 128, u2, 128, 128, M, 256);
    agg_bf<128><<<gagg, 256, 0, stream>>>(t2, csr_src, row_start, deg, agg2, M);
    ew_k<128, 1><<<(M * 128 / 8 + 255) / 256, 256, 0, stream>>>(
        agg2, u2, b2, h2, M * 128 / 8);

    // ---- layer 3: [t3|u3] = h2@Wcat3, agg3 = agg(t3), out = sigmoid(agg3+u3+b3)
    mgemm<64, 64, 2, 2, 0><<<dim3(gm64, 2), 256, 0, stream>>>(
        h2, Wcat3T, 128, nullptr, nullptr, 0, nullptr,
        t3, 64, u3, 64, 64, M, 128);
    agg_bf<64><<<gagg, 256, 0, stream>>>(t3, csr_src, row_start, deg, agg3, M);
    ew_k<64, 2><<<(M * 64 / 8 + 255) / 256, 256, 0, stream>>>(
        agg3, u3, b3, (float*)d_out, M * 64 / 8);
}